// Round 7
// baseline (589.185 us; speedup 1.0000x reference)
//
#include <hip/hip_runtime.h>
#include <stdint.h>
#include <math.h>

// B=4, T=2048, D=2048, HEADS=16.  Inputs/outputs fp32; internal bf16 MFMA.
//
// Pipeline: cast -> A: kv^T -> T: transpose -> B: scores -> S: softmax ->
//           C: q = a@vT^T -> D: perm(q)@w_dense^T + bias.
//
// GEMM core: 256x256 tile, uniform 32-k phases, ONE barrier per phase, with
// FRAGMENT PIPELINING (round-7 change): in segment p (executing MFMA of
// phase p), prefetch phase p+1's fragments -- B into an alternating register
// set (bx/by), A reloaded IN PLACE inside an mi-major cluster (a_mi's last
// use is its own 4-MFMA block; reload issued right after it).  This breaks
// the WAR hazard that serialized RD-burst and MFMA-cluster in rounds 4-6
// (measured: LDS 2313 cyc + MFMA 2484 cyc per K-tile/CU ~= the observed 4331
// -> pipes serial -> 53% MfmaUtil).  Now ds_reads issue during the cluster.
//
// Region/ledger (regions per operand r_q, q=0..3: buf=q>>1, kh=q&1; phase p
// consumes r_{p%4}; 4 loads per segment; NP = K/32 phases):
//  segment p = [BAR(p-1) .. BAR(p)]:
//    STG4 -> r_{p%4} @elem 32*(p+4)   (data for phase p+4)
//    RDB4(alt) + mi-major CLUSTER{ MFMA4(a_mi) ; a_mi = RDA(mi) } from r_{(p+1)%4}
//    VM(8); BAR(p)
//  data-ready: r_{(p+1)%4} staged at seg p-3; VM(8) at end of seg p-1 leaves
//   only segs p-2,p-1 (8) outstanding -> forces seg p-3; BAR(p-1) publishes;
//   reads sit after BAR(p-1).  OK for all p.
//  anti-dep: r_{p%4}'s readers ran in segment p-1 (before BAR(p-1)); STG4
//   issues after BAR(p-1).  OK.  Pre-loop edge: phase-0 fragment reads happen
//   after the prologue barrier, and seg 0 overwrites r0 -> EXTRA BARRIER
//   between pre-loop reads and the loop.
//  prologue: STG r0@0 r1@32 r2@64 r3@96 (16 loads), VM(8) [forces r0,r1],
//   BAR, read phase-0 frags (B->bx, a0..7), BAR.
//  tail (phases NP-4..NP-1, no staging): VM(4) [forces seg NP-6], VM(0)
//   [forces seg NP-5], then barrier-free final two clusters.
//  accumulation order per acc[mi][ni] is phase-ordered as before -> bit-exact.
//
//  - 512 thr = 8 waves (2M x 4N), per-wave output 128x64 (acc[8][4] f32x4).
//  - LDS = 2dbuf x {A,B} x [2kh][256r x 32c] bf16 = 128 KiB dynamic.
//  - Staging: global_load_lds width=16, LINEAR LDS dest; global source chunk
//    g = (tid&3)^((tid>>3)&3) (involution with read-side XOR) -> 0 bank
//    conflicts (verified).
//  - Registers: a0..7 + bx0..3 + by0..3 = 16 frags (64 VGPR) + 128 acc;
//    __launch_bounds__(512,2) caps at 256 -> VGPR_Count is the spill canary.
//  - Grids: gridDim.x % 8 == 0, bn fastest => B-panels XCD-affine; no swizzle.

typedef __bf16 bf16x8 __attribute__((ext_vector_type(8)));
typedef float  f32x4  __attribute__((ext_vector_type(4)));

typedef __attribute__((address_space(3))) uint32_t lds_u32_t;
typedef __attribute__((address_space(1))) const uint32_t glb_u32_t;

__device__ __forceinline__ float bf2f(uint16_t u) {
  union { uint32_t i; float f; } c; c.i = ((uint32_t)u) << 16; return c.f;
}
__device__ __forceinline__ uint16_t f2bf(float f) {
  union { float f; uint32_t i; } c; c.f = f;
  uint32_t i = c.i;
  return (uint16_t)((i + 0x7fffu + ((i >> 16) & 1u)) >> 16);  // RNE
}

__device__ __forceinline__ void glds16(const uint16_t* g, const char* l) {
  __builtin_amdgcn_global_load_lds((glb_u32_t*)g, (lds_u32_t*)l, 16, 0, 0);
}

#define SCHED0() __builtin_amdgcn_sched_barrier(0)
#define BARRIER() do { SCHED0(); __builtin_amdgcn_s_barrier(); SCHED0(); } while (0)
#define VMCNT(n_) asm volatile("s_waitcnt vmcnt(" #n_ ")")

// ---- fused fp32 -> bf16 cast over x|w_qk|w_dense -----------------------------
#define NX4 4194304u
#define NW4 2097152u
#define ND4 1048576u
__global__ __launch_bounds__(256) void k_cast_all(
    const float* __restrict__ x, const float* __restrict__ wqk,
    const float* __restrict__ wd, uint16_t* __restrict__ dst) {
  uint32_t i = blockIdx.x * 256 + threadIdx.x;
  float4 v;
  if (i < NX4)            v = reinterpret_cast<const float4*>(x)[i];
  else if (i < NX4 + NW4) v = reinterpret_cast<const float4*>(wqk)[i - NX4];
  else                    v = reinterpret_cast<const float4*>(wd)[i - NX4 - NW4];
  ushort4 o;
  o.x = f2bf(v.x); o.y = f2bf(v.y); o.z = f2bf(v.z); o.w = f2bf(v.w);
  reinterpret_cast<ushort4*>(dst)[i] = o;
}

// ---- 256x256 GEMM core, fragment-pipelined uniform phases -------------------
// aR0/aR1/bR0/bR1: per-thread staging sources, rows (tid>>2) and (tid>>2)+128
// of the 256-row tile, at k=0, swizzled chunk offset already added.
__device__ __forceinline__ void gemm256_core(
    const uint16_t* aR0, const uint16_t* aR1,
    const uint16_t* bR0, const uint16_t* bR1,
    int K, f32x4 acc[8][4])
{
  extern __shared__ uint4 smem_u4[];
  char* smem = (char*)smem_u4;
  const int tid = threadIdx.x;
  const int w = tid >> 6, l = tid & 63;
  const int wm = (w >> 2) * 128, wn = (w & 3) * 64;
  const int frow = l & 15, fkc = l >> 4;
  // read-side chunk swizzle: chunk' = fkc ^ ((frow>>1)&3)  (fixed per lane)
  const uint32_t chunk = (uint32_t)((fkc ^ ((frow >> 1) & 3)) * 16);
  const uint32_t aBase = (uint32_t)(wm + frow) * 64 + chunk;           // +mi*1024 +ROFF(q)
  const uint32_t bBase = 65536u + (uint32_t)(wn + frow) * 64 + chunk;  // +ni*1024 +ROFF(q)
  char* lW = smem + (uint32_t)w * 1024u;   // per-wave staging dest base
  const int NIT = (K >> 7) - 1;            // steady 4-segment iterations; K%128==0, K>=256

#define ROFF(q_) ((uint32_t)((q_) & 1) * 16384u + (uint32_t)((q_) >> 1) * 32768u)
#define RDA(mi_, q_) \
    (*reinterpret_cast<const bf16x8*>(smem + (aBase + (mi_) * 1024u + ROFF(q_))))
#define RDB(ni_, q_) \
    (*reinterpret_cast<const bf16x8*>(smem + (bBase + (ni_) * 1024u + ROFF(q_))))
#define RDB4(D0_, D1_, D2_, D3_, q_) do { \
    D0_ = RDB(0, q_); D1_ = RDB(1, q_); D2_ = RDB(2, q_); D3_ = RDB(3, q_); } while (0)
#define STG4(off_, q_) do { \
    glds16(aR0 + (off_), lW + ROFF(q_)); \
    glds16(aR1 + (off_), lW + (ROFF(q_) + 8192u)); \
    glds16(bR0 + (off_), lW + (65536u + ROFF(q_))); \
    glds16(bR1 + (off_), lW + (65536u + ROFF(q_) + 8192u)); } while (0)
#define MFMA4(ai_, mi_, B0_, B1_, B2_, B3_) do { \
    acc[mi_][0] = __builtin_amdgcn_mfma_f32_16x16x32_bf16(ai_, B0_, acc[mi_][0], 0, 0, 0); \
    acc[mi_][1] = __builtin_amdgcn_mfma_f32_16x16x32_bf16(ai_, B1_, acc[mi_][1], 0, 0, 0); \
    acc[mi_][2] = __builtin_amdgcn_mfma_f32_16x16x32_bf16(ai_, B2_, acc[mi_][2], 0, 0, 0); \
    acc[mi_][3] = __builtin_amdgcn_mfma_f32_16x16x32_bf16(ai_, B3_, acc[mi_][3], 0, 0, 0); \
  } while (0)
// mi-major cluster; after each a_mi's block, reload it in place from region qn_
#define CLUST_RD(qn_, B0_, B1_, B2_, B3_) do { \
    __builtin_amdgcn_s_setprio(1); \
    MFMA4(a0, 0, B0_, B1_, B2_, B3_); a0 = RDA(0, qn_); \
    MFMA4(a1, 1, B0_, B1_, B2_, B3_); a1 = RDA(1, qn_); \
    MFMA4(a2, 2, B0_, B1_, B2_, B3_); a2 = RDA(2, qn_); \
    MFMA4(a3, 3, B0_, B1_, B2_, B3_); a3 = RDA(3, qn_); \
    MFMA4(a4, 4, B0_, B1_, B2_, B3_); a4 = RDA(4, qn_); \
    MFMA4(a5, 5, B0_, B1_, B2_, B3_); a5 = RDA(5, qn_); \
    MFMA4(a6, 6, B0_, B1_, B2_, B3_); a6 = RDA(6, qn_); \
    MFMA4(a7, 7, B0_, B1_, B2_, B3_); a7 = RDA(7, qn_); \
    __builtin_amdgcn_s_setprio(0); } while (0)
#define CLUST_END(B0_, B1_, B2_, B3_) do { \
    __builtin_amdgcn_s_setprio(1); \
    MFMA4(a0, 0, B0_, B1_, B2_, B3_); MFMA4(a1, 1, B0_, B1_, B2_, B3_); \
    MFMA4(a2, 2, B0_, B1_, B2_, B3_); MFMA4(a3, 3, B0_, B1_, B2_, B3_); \
    MFMA4(a4, 4, B0_, B1_, B2_, B3_); MFMA4(a5, 5, B0_, B1_, B2_, B3_); \
    MFMA4(a6, 6, B0_, B1_, B2_, B3_); MFMA4(a7, 7, B0_, B1_, B2_, B3_); \
    __builtin_amdgcn_s_setprio(0); } while (0)
// steady segment: stage phase p+4, prefetch phase p+1 frags, run phase p
#define SEG_STD(off_, q_, qn_, BC0, BC1, BC2, BC3, BA0, BA1, BA2, BA3) do { \
    STG4(off_, q_); \
    RDB4(BA0, BA1, BA2, BA3, qn_); \
    CLUST_RD(qn_, BC0, BC1, BC2, BC3); \
    VMCNT(8); \
    BARRIER(); } while (0)

  // ---- prologue: stage r0@0 r1@32 r2@64 r3@96; read phase-0 fragments -------
  STG4(0, 0); STG4(32, 1); STG4(64, 2); STG4(96, 3);
  VMCNT(8);        // forces r0,r1 (oldest 8 of 16)
  BARRIER();       // publish r0,r1

  bf16x8 a0, a1, a2, a3, a4, a5, a6, a7;
  bf16x8 bx0, bx1, bx2, bx3, by0, by1, by2, by3;
  RDB4(bx0, bx1, bx2, bx3, 0);
  a0 = RDA(0, 0); a1 = RDA(1, 0); a2 = RDA(2, 0); a3 = RDA(3, 0);
  a4 = RDA(4, 0); a5 = RDA(5, 0); a6 = RDA(6, 0); a7 = RDA(7, 0);
  BARRIER();       // pre-loop reads of r0 complete before seg 0 overwrites r0

  // ---- steady state: 4 uniform segments / iteration --------------------------
  for (int it = 0; it < NIT; ++it) {
    SEG_STD(128, 0, 1, bx0, bx1, bx2, bx3, by0, by1, by2, by3);
    SEG_STD(160, 1, 2, by0, by1, by2, by3, bx0, bx1, bx2, bx3);
    SEG_STD(192, 2, 3, bx0, bx1, bx2, bx3, by0, by1, by2, by3);
    SEG_STD(224, 3, 0, by0, by1, by2, by3, bx0, bx1, bx2, bx3);
    aR0 += 128; aR1 += 128; bR0 += 128; bR1 += 128;
  }

  // ---- tail: phases NP-4..NP-1, no staging ----------------------------------
  RDB4(by0, by1, by2, by3, 1); CLUST_RD(1, bx0, bx1, bx2, bx3); VMCNT(4); BARRIER();
  RDB4(bx0, bx1, bx2, bx3, 2); CLUST_RD(2, by0, by1, by2, by3); VMCNT(0); BARRIER();
  RDB4(by0, by1, by2, by3, 3); CLUST_RD(3, bx0, bx1, bx2, bx3);
  CLUST_END(by0, by1, by2, by3);
#undef ROFF
#undef RDA
#undef RDB
#undef RDB4
#undef STG4
#undef MFMA4
#undef CLUST_RD
#undef CLUST_END
#undef SEG_STD
}

// staging source-column swizzle (involution with read side): g = (tid&3)^((tid>>3)&3)
__device__ __forceinline__ int stage_co() {
  const int tid = threadIdx.x;
  return (((tid & 3) ^ ((tid >> 3) & 3)) * 8);
}

// ---- stage A: kv^T, block-uniform split-store into k0T / vT ------------------
__global__ __launch_bounds__(512, 2) void k_gemm_kv(
    const uint16_t* __restrict__ W,    // wqkb 4096x2048
    const uint16_t* __restrict__ X,    // xb   8192x2048
    uint16_t* __restrict__ k0T,        // 2048x8192
    uint16_t* __restrict__ vT)         // 2048x8192
{
  const int tid = threadIdx.x;
  const int bm = blockIdx.y, bn = blockIdx.x;
  const int r0 = tid >> 2, co = stage_co();
  const uint16_t* aR0 = W + (size_t)(bm * 256 + r0) * 2048 + co;
  const uint16_t* aR1 = W + (size_t)(bm * 256 + 128 + r0) * 2048 + co;
  const uint16_t* bR0 = X + (size_t)(bn * 256 + r0) * 2048 + co;
  const uint16_t* bR1 = X + (size_t)(bn * 256 + 128 + r0) * 2048 + co;
  f32x4 acc[8][4];
#pragma unroll
  for (int i = 0; i < 8; ++i)
#pragma unroll
    for (int j = 0; j < 4; ++j) acc[i][j] = (f32x4){0.f, 0.f, 0.f, 0.f};
  gemm256_core(aR0, aR1, bR0, bR1, 2048, acc);
  const int w = tid >> 6, l = tid & 63;
  const int wm = (w >> 2) * 128, wn = (w & 3) * 64;
  const int cr = (l >> 4) * 4, cc = l & 15;
  uint16_t* Cb = (bm < 8) ? k0T : vT;
  const int rb = (bm & 7) * 256;
#pragma unroll
  for (int mi = 0; mi < 8; ++mi)
#pragma unroll
    for (int ni = 0; ni < 4; ++ni)
#pragma unroll
      for (int g = 0; g < 4; ++g) {
        int lr = rb + wm + mi * 16 + cr + g;
        int bt = bn * 256 + wn + ni * 16 + cc;
        Cb[(size_t)lr * 8192 + bt] = f2bf(acc[mi][ni][g]);
      }
}

// ---- generic batched A@B^T (both K-contig), scaled bf16 store ----------------
__global__ __launch_bounds__(512, 2) void k_gemm_bt(
    const uint16_t* __restrict__ A, int lda, long sA,
    const uint16_t* __restrict__ B, int ldb, long sB,
    uint16_t* __restrict__ C, int ldc, long sC,
    int K, float scale)
{
  const int z = blockIdx.z;
  A += (size_t)z * sA; B += (size_t)z * sB; C += (size_t)z * sC;
  const int tid = threadIdx.x;
  const int bm = blockIdx.y, bn = blockIdx.x;
  const int r0 = tid >> 2, co = stage_co();
  const uint16_t* aR0 = A + (size_t)(bm * 256 + r0) * lda + co;
  const uint16_t* aR1 = A + (size_t)(bm * 256 + 128 + r0) * lda + co;
  const uint16_t* bR0 = B + (size_t)(bn * 256 + r0) * ldb + co;
  const uint16_t* bR1 = B + (size_t)(bn * 256 + 128 + r0) * ldb + co;
  f32x4 acc[8][4];
#pragma unroll
  for (int i = 0; i < 8; ++i)
#pragma unroll
    for (int j = 0; j < 4; ++j) acc[i][j] = (f32x4){0.f, 0.f, 0.f, 0.f};
  gemm256_core(aR0, aR1, bR0, bR1, K, acc);
  const int w = tid >> 6, l = tid & 63;
  const int wm = (w >> 2) * 128, wn = (w & 3) * 64;
  const int cr = (l >> 4) * 4, cc = l & 15;
#pragma unroll
  for (int mi = 0; mi < 8; ++mi)
#pragma unroll
    for (int ni = 0; ni < 4; ++ni)
#pragma unroll
      for (int g = 0; g < 4; ++g) {
        int grow = bm * 256 + wm + mi * 16 + cr + g;
        int gcol = bn * 256 + wn + ni * 16 + cc;
        C[(size_t)grow * ldc + gcol] = f2bf(acc[mi][ni][g] * scale);
      }
}

// ---- stage D: permuted-A GEMM + fp32 bias/store into d_out -------------------
__device__ __forceinline__ size_t qrow_off(int rr) {
  // rr = b'*2048 + t' ; q row = (b_i, i), b_i=(t'>>4)&3, i=(t'&15)*128+b'*32+(t'>>6)
  int bp = rr >> 11, tp = rr & 2047;
  int bi = (tp >> 4) & 3;
  int i  = (tp & 15) * 128 + bp * 32 + (tp >> 6);
  return ((size_t)bi * 2048 + (size_t)i) * 2048;
}

__global__ __launch_bounds__(512, 2) void k_gemm_out(
    const uint16_t* __restrict__ Q,     // qb (4,2048,2048) bf16
    const uint16_t* __restrict__ W,     // wdb 2048x2048 bf16
    const float*    __restrict__ bias,  // b_dense fp32 (2048)
    float*          __restrict__ Out)   // d_out 8192x2048 fp32
{
  const int tid = threadIdx.x;
  const int bm = blockIdx.y, bn = blockIdx.x;
  const int r0 = tid >> 2, co = stage_co();
  const uint16_t* aR0 = Q + qrow_off(bm * 256 + r0) + co;
  const uint16_t* aR1 = Q + qrow_off(bm * 256 + 128 + r0) + co;
  const uint16_t* bR0 = W + (size_t)(bn * 256 + r0) * 2048 + co;
  const uint16_t* bR1 = W + (size_t)(bn * 256 + 128 + r0) * 2048 + co;
  f32x4 acc[8][4];
#pragma unroll
  for (int i = 0; i < 8; ++i)
#pragma unroll
    for (int j = 0; j < 4; ++j) acc[i][j] = (f32x4){0.f, 0.f, 0.f, 0.f};
  gemm256_core(aR0, aR1, bR0, bR1, 2048, acc);
  const int w = tid >> 6, l = tid & 63;
  const int wm = (w >> 2) * 128, wn = (w & 3) * 64;
  const int cr = (l >> 4) * 4, cc = l & 15;
#pragma unroll
  for (int mi = 0; mi < 8; ++mi)
#pragma unroll
    for (int ni = 0; ni < 4; ++ni)
#pragma unroll
      for (int g = 0; g < 4; ++g) {
        int grow = bm * 256 + wm + mi * 16 + cr + g;
        int gcol = bn * 256 + wn + ni * 16 + cc;
        Out[(size_t)grow * 2048 + gcol] = acc[mi][ni][g] + bias[gcol];
      }
}

// ---- transpose vT (2048x8192) -> Vn (8192x2048) ------------------------------
__global__ __launch_bounds__(256) void k_transpose(
    const uint16_t* __restrict__ src, uint16_t* __restrict__ dst)
{
  __shared__ uint16_t tile[64][65];
  const int tid = threadIdx.x;
  const int bx = blockIdx.x;
  const int by = blockIdx.y;
  const int cu = tid & 31, r0 = tid >> 5;
#pragma unroll
  for (int p = 0; p < 8; ++p) {
    int r = p * 8 + r0;
    uint32_t v = *reinterpret_cast<const uint32_t*>(
        &src[(size_t)(by * 64 + r) * 8192 + bx * 64 + cu * 2]);
    tile[r][cu * 2]     = (uint16_t)(v & 0xffffu);
    tile[r][cu * 2 + 1] = (uint16_t)(v >> 16);
  }
  __syncthreads();
#pragma unroll
  for (int p = 0; p < 8; ++p) {
    int r = p * 8 + r0;
    uint32_t lo = tile[cu * 2][r], hi = tile[cu * 2 + 1][r];
    *reinterpret_cast<uint32_t*>(
        &dst[(size_t)(bx * 64 + r) * 2048 + by * 64 + cu * 2]) = lo | (hi << 16);
  }
}

// ---- row softmax (bf16 in place), 1 block per row of 2048 --------------------
__global__ __launch_bounds__(256) void k_softmax(uint16_t* __restrict__ s)
{
  uint16_t* p = s + (size_t)blockIdx.x * 2048;
  const int tid = threadIdx.x;
  uint4 raw = reinterpret_cast<const uint4*>(p)[tid];
  uint32_t u[4] = {raw.x, raw.y, raw.z, raw.w};
  float x[8];
#pragma unroll
  for (int i = 0; i < 4; ++i) {
    x[2 * i]     = bf2f((uint16_t)(u[i] & 0xffffu));
    x[2 * i + 1] = bf2f((uint16_t)(u[i] >> 16));
  }
  float m = x[0];
#pragma unroll
  for (int i = 1; i < 8; ++i) m = fmaxf(m, x[i]);
#pragma unroll
  for (int o = 32; o; o >>= 1) m = fmaxf(m, __shfl_xor(m, o, 64));
  __shared__ float redm[4], reds[4];
  if ((tid & 63) == 0) redm[tid >> 6] = m;
  __syncthreads();
  m = fmaxf(fmaxf(redm[0], redm[1]), fmaxf(redm[2], redm[3]));
  float sum = 0.f;
#pragma unroll
  for (int i = 0; i < 8; ++i) { x[i] = __expf(x[i] - m); sum += x[i]; }
#pragma unroll
  for (int o = 32; o; o >>= 1) sum += __shfl_xor(sum, o, 64);
  if ((tid & 63) == 0) reds[tid >> 6] = sum;
  __syncthreads();
  sum = reds[0] + reds[1] + reds[2] + reds[3];
  float inv = 1.0f / sum;
  uint32_t ou[4];
#pragma unroll
  for (int i = 0; i < 4; ++i) {
    uint32_t lo = f2bf(x[2 * i] * inv);
    uint32_t hi = f2bf(x[2 * i + 1] * inv);
    ou[i] = lo | (hi << 16);
  }
  reinterpret_cast<uint4*>(p)[tid] = make_uint4(ou[0], ou[1], ou[2], ou[3]);
}

// ------------------------------------------------------------------------------
extern "C" void kernel_launch(void* const* d_in, const int* in_sizes, int n_in,
                              void* d_out, int out_size, void* d_ws, size_t ws_size,
                              hipStream_t stream) {
  const float* x       = (const float*)d_in[0];
  const float* w_qk    = (const float*)d_in[1];
  const float* w_dense = (const float*)d_in[2];
  const float* b_dense = (const float*)d_in[3];
  float* out = (float*)d_out;

  static int attr_done = 0;
  if (!attr_done) {
    (void)hipFuncSetAttribute(reinterpret_cast<const void*>(k_gemm_kv),
                              hipFuncAttributeMaxDynamicSharedMemorySize, 131072);
    (void)hipFuncSetAttribute(reinterpret_cast<const void*>(k_gemm_bt),
                              hipFuncAttributeMaxDynamicSharedMemorySize, 131072);
    (void)hipFuncSetAttribute(reinterpret_cast<const void*>(k_gemm_out),
                              hipFuncAttributeMaxDynamicSharedMemorySize, 131072);
    attr_done = 1;
  }

  const size_t NX = 4ull * 2048 * 2048;
  const size_t NW = 4096ull * 2048;
  const size_t ND = 2048ull * 2048;

  // d_ws layout (bf16): xb | wqkb | wdb | k0T | vT   (126 MB peak)
  uint16_t* xb   = (uint16_t*)d_ws;
  uint16_t* wqkb = xb + NX;
  uint16_t* wdb  = wqkb + NW;
  uint16_t* k0T  = wdb + ND;
  uint16_t* vT   = k0T + NX;
  uint16_t* qb   = xb;                    // alias: xb dead after stage A
  uint16_t* Vn   = (uint16_t*)d_out;      // d_out as scratch (dead before D)
  uint16_t* sb   = Vn + NX;

  const float scale = (float)(1.0 / sqrt(0.5 * 2048.0 * 2047.0));

  k_cast_all<<<dim3((NX4 + NW4 + ND4) / 256), 256, 0, stream>>>(x, w_qk, w_dense, xb);

  // A: kv^T  (M=4096 e, N=8192 bt, K=2048)
  k_gemm_kv<<<dim3(32, 16), 512, 131072, stream>>>(wqkb, xb, k0T, vT);
  // T: vT -> Vn
  k_transpose<<<dim3(128, 32), 256, 0, stream>>>(vT, Vn);
  // B: s = scale * k0T @ Vn^T
  k_gemm_bt<<<dim3(8, 8, 4), 512, 131072, stream>>>(
      k0T, 8192, 2048L, Vn, 2048, 2048L * 2048L, sb, 2048, 2048L * 2048L, 2048, scale);
  // S: softmax rows
  k_softmax<<<dim3(8192), 256, 0, stream>>>(sb);
  // C: q = a @ vT^T
  k_gemm_bt<<<dim3(8, 8, 4), 512, 131072, stream>>>(
      sb, 2048, 2048L * 2048L, vT, 8192, 2048L, qb, 2048, 2048L * 2048L, 2048, 1.0f);
  // D: out = perm(q) @ w_dense^T + bias -> fp32
  k_gemm_out<<<dim3(8, 32), 512, 131072, stream>>>(qb, wdb, b_dense, out);
}

// Round 8
// 498.526 us; speedup vs baseline: 1.1819x; 1.1819x over previous
//
#include <hip/hip_runtime.h>
#include <stdint.h>
#include <math.h>

// B=4, T=2048, D=2048, HEADS=16.  Inputs/outputs fp32; internal bf16 MFMA.
//
// Pipeline: cast -> A: kv^T -> T: transpose -> B: scores -> S: softmax ->
//           C: q = a@vT^T -> D: perm(q)@w_dense^T + bias.
//
// GEMM core: ROUND-5 schedule (empirical best: one barrier per phase, RD
// before barrier, prioritized MFMA cluster after, vmcnt(8) per phase) ported
// to v_mfma_f32_32x32x16_bf16 (ROUND-8 single change).  Round 7's in-cluster
// ds_read interleave REGRESSED (41% MfmaUtil): per-MFMA lgkmcnt deps broke
// back-to-back MFMA issue -> reverted.  Shape change instead: same FLOP at
// 4061 vs 3378 FLOP/cyc pipe rate (m119) and HALF the MFMA instructions
// (8/phase vs 16), freeing issue slots for the ds_read stream.
//
// Fragment layouts (guide §3; C/D m74/m101-verified):
//  A (32x16): lane l -> row l%32, k = 8*(l/32)+i   (family-consistent with
//    the 16x16x32 mapping this kernel already uses: row l%16, k 8*(l/16)+i)
//  B (16x32): lane l -> col l%32, k = 8*(l/32)+i
//  C/D: col = lane&31, row = (reg&3) + 8*(reg>>2) + 4*(lane>>5), reg 0..15
// Per wave: 4x2 blocks of 32x32 -> acc f32x16[4][2] (128 regs, unchanged).
// Reads: frag (blk m, kstep s in the 32k region) at row wm+m*32+(l&31),
// global chunk (l>>5)+2s; LDS chunk ^= (row>>1)&3 = (l>>1)&3 (wm, 32m, wn
// all == 0 mod 8) -> byte = rowbase + (chunk16 ^ 32s), chunk16 =
// 16*((l>>5)^((l>>1)&3)).  Same 2-way-free bank pattern as the 16x16 reads
// (measured 0 conflicts); SQ_LDS_BANK_CONFLICT is the canary.
//
// Ledger/regions/staging/vmcnt: byte-identical to round 5 (one barrier per
// phase; VMCNT(8) steady, 8->4->0 tail; STG slots @96/@128/@160/@192; region
// = (op,kh) 16 KiB quarter; anti-dep/data-ready proofs carried over).
//
//  - 512 thr = 8 waves (2M x 4N), per-wave output 128x64.
//  - LDS = 2dbuf x {A,B} x [2kh][256r x 32c] bf16 = 128 KiB dynamic.
//  - Staging: global_load_lds width=16, LINEAR LDS dest; source chunk
//    g = (tid&3)^((tid>>3)&3) (involution with read-side XOR).
//  - Grids: gridDim.x % 8 == 0, bn fastest => B-panels XCD-affine; no swizzle.

typedef __bf16 bf16x8 __attribute__((ext_vector_type(8)));
typedef float  f32x16 __attribute__((ext_vector_type(16)));

typedef __attribute__((address_space(3))) uint32_t lds_u32_t;
typedef __attribute__((address_space(1))) const uint32_t glb_u32_t;

__device__ __forceinline__ float bf2f(uint16_t u) {
  union { uint32_t i; float f; } c; c.i = ((uint32_t)u) << 16; return c.f;
}
__device__ __forceinline__ uint16_t f2bf(float f) {
  union { float f; uint32_t i; } c; c.f = f;
  uint32_t i = c.i;
  return (uint16_t)((i + 0x7fffu + ((i >> 16) & 1u)) >> 16);  // RNE
}

__device__ __forceinline__ void glds16(const uint16_t* g, const char* l) {
  __builtin_amdgcn_global_load_lds((glb_u32_t*)g, (lds_u32_t*)l, 16, 0, 0);
}

#define SCHED0() __builtin_amdgcn_sched_barrier(0)
#define BARRIER() do { SCHED0(); __builtin_amdgcn_s_barrier(); SCHED0(); } while (0)
#define VMCNT(n_) asm volatile("s_waitcnt vmcnt(" #n_ ")")

// ---- fused fp32 -> bf16 cast over x|w_qk|w_dense -----------------------------
#define NX4 4194304u
#define NW4 2097152u
#define ND4 1048576u
__global__ __launch_bounds__(256) void k_cast_all(
    const float* __restrict__ x, const float* __restrict__ wqk,
    const float* __restrict__ wd, uint16_t* __restrict__ dst) {
  uint32_t i = blockIdx.x * 256 + threadIdx.x;
  float4 v;
  if (i < NX4)            v = reinterpret_cast<const float4*>(x)[i];
  else if (i < NX4 + NW4) v = reinterpret_cast<const float4*>(wqk)[i - NX4];
  else                    v = reinterpret_cast<const float4*>(wd)[i - NX4 - NW4];
  ushort4 o;
  o.x = f2bf(v.x); o.y = f2bf(v.y); o.z = f2bf(v.z); o.w = f2bf(v.w);
  reinterpret_cast<ushort4*>(dst)[i] = o;
}

// ---- 256x256 GEMM core (32x32x16 MFMA), round-5 schedule --------------------
// aR0/aR1/bR0/bR1: per-thread staging sources, rows (tid>>2) and (tid>>2)+128
// of the 256-row tile, at k=0, swizzled chunk offset already added.
__device__ __forceinline__ void gemm256_core(
    const uint16_t* aR0, const uint16_t* aR1,
    const uint16_t* bR0, const uint16_t* bR1,
    int K, f32x16 acc[4][2])
{
  extern __shared__ uint4 smem_u4[];
  char* smem = (char*)smem_u4;
  const int tid = threadIdx.x;
  const int w = tid >> 6, l = tid & 63;
  const int wm = (w >> 2) * 128, wn = (w & 3) * 64;
  const uint32_t chunk16 = 16u * (uint32_t)((l >> 5) ^ ((l >> 1) & 3));
  const uint32_t aBase = (uint32_t)(wm + (l & 31)) * 64 + chunk16;           // +m*2048 +(^32s) +kh*16384 +buf*32768
  const uint32_t bBase = 65536u + (uint32_t)(wn + (l & 31)) * 64 + chunk16;  // +n*2048 +(^32s) ...
  char* lW = smem + (uint32_t)w * 1024u;   // per-wave staging dest base
  const int NIT = K >> 7;                  // iterations of 2 K-tiles; K % 128 == 0

#define LDSA(kh_, buf_, half_) (lW + ((buf_) * 32768u + (kh_) * 16384u + (half_) * 8192u))
#define LDSB(kh_, buf_, half_) (lW + (65536u + (buf_) * 32768u + (kh_) * 16384u + (half_) * 8192u))
// off_ is the FULL K-offset in elements (tile*64 + kh*32); kh_ selects the LDS
// destination region only.
#define STG_A(off_, kh_, buf_) do { \
    glds16(aR0 + (off_), LDSA(kh_, buf_, 0)); \
    glds16(aR1 + (off_), LDSA(kh_, buf_, 1)); } while (0)
#define STG_B(off_, kh_, buf_) do { \
    glds16(bR0 + (off_), LDSB(kh_, buf_, 0)); \
    glds16(bR1 + (off_), LDSB(kh_, buf_, 1)); } while (0)
// frag read: block m_/n_ (32 rows), kstep s_ (16k) within region (kh_, buf_)
#define RDA(m_, s_, kh_, buf_) \
    (*reinterpret_cast<const bf16x8*>(smem + ((aBase ^ ((s_) * 32u)) + (m_) * 2048u + (kh_) * 16384u + (buf_) * 32768u)))
#define RDB(n_, s_, kh_, buf_) \
    (*reinterpret_cast<const bf16x8*>(smem + ((bBase ^ ((s_) * 32u)) + (n_) * 2048u + (kh_) * 16384u + (buf_) * 32768u)))
// P1 reads: A blocks 0,1 (both ksteps) + all B frags; P2: A blocks 2,3.
#define PH_RD8(kh_, buf_) do { \
    a00 = RDA(0, 0, kh_, buf_); a01 = RDA(0, 1, kh_, buf_); \
    a10 = RDA(1, 0, kh_, buf_); a11 = RDA(1, 1, kh_, buf_); \
    b00 = RDB(0, 0, kh_, buf_); b01 = RDB(0, 1, kh_, buf_); \
    b10 = RDB(1, 0, kh_, buf_); b11 = RDB(1, 1, kh_, buf_); } while (0)
#define PH_RD4(kh_, buf_) do { \
    a00 = RDA(2, 0, kh_, buf_); a01 = RDA(2, 1, kh_, buf_); \
    a10 = RDA(3, 0, kh_, buf_); a11 = RDA(3, 1, kh_, buf_); } while (0)
// 8 MFMAs: two consecutive row-blocks (r0_, r0_+1) x 2 col-blocks x 2 ksteps
#define MFMA8(r0_) do { \
    acc[(r0_)+0][0] = __builtin_amdgcn_mfma_f32_32x32x16_bf16(a00, b00, acc[(r0_)+0][0], 0, 0, 0); \
    acc[(r0_)+0][0] = __builtin_amdgcn_mfma_f32_32x32x16_bf16(a01, b01, acc[(r0_)+0][0], 0, 0, 0); \
    acc[(r0_)+1][0] = __builtin_amdgcn_mfma_f32_32x32x16_bf16(a10, b00, acc[(r0_)+1][0], 0, 0, 0); \
    acc[(r0_)+1][0] = __builtin_amdgcn_mfma_f32_32x32x16_bf16(a11, b01, acc[(r0_)+1][0], 0, 0, 0); \
    acc[(r0_)+0][1] = __builtin_amdgcn_mfma_f32_32x32x16_bf16(a00, b10, acc[(r0_)+0][1], 0, 0, 0); \
    acc[(r0_)+0][1] = __builtin_amdgcn_mfma_f32_32x32x16_bf16(a01, b11, acc[(r0_)+0][1], 0, 0, 0); \
    acc[(r0_)+1][1] = __builtin_amdgcn_mfma_f32_32x32x16_bf16(a10, b10, acc[(r0_)+1][1], 0, 0, 0); \
    acc[(r0_)+1][1] = __builtin_amdgcn_mfma_f32_32x32x16_bf16(a11, b11, acc[(r0_)+1][1], 0, 0, 0); \
  } while (0)
// ONE barrier per phase: data-ready gate, then prioritized MFMA cluster.
#define MFMA_PH(r0_) do { \
    BARRIER(); \
    __builtin_amdgcn_s_setprio(1); \
    MFMA8(r0_); \
    __builtin_amdgcn_s_setprio(0); } while (0)

  // ---- prologue: tile0 kh0@0 kh1@32 + tile1 kh0@64 --------------------------
  STG_A(0, 0, 0); STG_B(0, 0, 0); STG_A(32, 1, 0); STG_B(32, 1, 0);
  STG_A(64, 0, 1); STG_B(64, 0, 1);
  VMCNT(4);

  bf16x8 a00, a01, a10, a11, b00, b01, b10, b11;
  BARRIER();   // BAR0: t0 data published to all waves

  // ---- steady state: branch-free, 2 K-tiles / iteration ----------------------
  for (int it = 0; it < NIT - 1; ++it) {
    // ===== tile t0 (buf 0) =====
    PH_RD8(0, 0); STG_A(96, 1, 1);            MFMA_PH(0);   // P1
    PH_RD4(0, 0); STG_B(96, 1, 1); VMCNT(8);  MFMA_PH(2);   // P2 -> t0.kh1 ready
    PH_RD8(1, 0); STG_A(128, 0, 0);           MFMA_PH(0);   // P3
    PH_RD4(1, 0); STG_B(128, 0, 0); VMCNT(8); MFMA_PH(2);   // P4 -> t1.kh0 ready
    // ===== tile t1 (buf 1) =====
    PH_RD8(0, 1); STG_A(160, 1, 0);           MFMA_PH(0);   // P5
    PH_RD4(0, 1); STG_B(160, 1, 0); VMCNT(8); MFMA_PH(2);   // P6 -> t1.kh1 ready
    PH_RD8(1, 1); STG_A(192, 0, 1);           MFMA_PH(0);   // P7
    PH_RD4(1, 1); STG_B(192, 0, 1); VMCNT(8); MFMA_PH(2);   // P8 -> t2.kh0 ready
    aR0 += 128; aR1 += 128; bR0 += 128; bR1 += 128;
  }

  // ---- tail: last 2 tiles (t0 buf0 / t1 buf1); only A/B(t1,kh1)@96 to stage --
  PH_RD8(0, 0); STG_A(96, 1, 1);            MFMA_PH(0);
  PH_RD4(0, 0); STG_B(96, 1, 1); VMCNT(8);  MFMA_PH(2);     // -> t0.kh1 ready
  PH_RD8(1, 0);                             MFMA_PH(0);
  PH_RD4(1, 0); VMCNT(4);                   MFMA_PH(2);     // -> t1.kh0 ready
  PH_RD8(0, 1);                             MFMA_PH(0);
  PH_RD4(0, 1); VMCNT(0);                   MFMA_PH(2);     // -> t1.kh1 ready
  PH_RD8(1, 1);                             MFMA_PH(0);
  PH_RD4(1, 1);                             MFMA_PH(2);
#undef LDSA
#undef LDSB
#undef STG_A
#undef STG_B
#undef RDA
#undef RDB
#undef PH_RD8
#undef PH_RD4
#undef MFMA8
#undef MFMA_PH
}

// staging source-column swizzle (involution with read side): g = (tid&3)^((tid>>3)&3)
__device__ __forceinline__ int stage_co() {
  const int tid = threadIdx.x;
  return (((tid & 3) ^ ((tid >> 3) & 3)) * 8);
}

// C/D row-within-block for reg g, lane l: (g&3) + 8*(g>>2) + 4*(l>>5)
__device__ __forceinline__ int cd_row(int g, int l) {
  return (g & 3) + 8 * (g >> 2) + 4 * (l >> 5);
}

// ---- stage A: kv^T, block-uniform split-store into k0T / vT ------------------
__global__ __launch_bounds__(512, 2) void k_gemm_kv(
    const uint16_t* __restrict__ W,    // wqkb 4096x2048
    const uint16_t* __restrict__ X,    // xb   8192x2048
    uint16_t* __restrict__ k0T,        // 2048x8192
    uint16_t* __restrict__ vT)         // 2048x8192
{
  const int tid = threadIdx.x;
  const int bm = blockIdx.y, bn = blockIdx.x;
  const int r0 = tid >> 2, co = stage_co();
  const uint16_t* aR0 = W + (size_t)(bm * 256 + r0) * 2048 + co;
  const uint16_t* aR1 = W + (size_t)(bm * 256 + 128 + r0) * 2048 + co;
  const uint16_t* bR0 = X + (size_t)(bn * 256 + r0) * 2048 + co;
  const uint16_t* bR1 = X + (size_t)(bn * 256 + 128 + r0) * 2048 + co;
  f32x16 acc[4][2];
#pragma unroll
  for (int i = 0; i < 4; ++i)
#pragma unroll
    for (int j = 0; j < 2; ++j)
#pragma unroll
      for (int g = 0; g < 16; ++g) acc[i][j][g] = 0.f;
  gemm256_core(aR0, aR1, bR0, bR1, 2048, acc);
  const int w = tid >> 6, l = tid & 63;
  const int wm = (w >> 2) * 128, wn = (w & 3) * 64;
  uint16_t* Cb = (bm < 8) ? k0T : vT;
  const int rb = (bm & 7) * 256;
#pragma unroll
  for (int mi = 0; mi < 4; ++mi)
#pragma unroll
    for (int ni = 0; ni < 2; ++ni)
#pragma unroll
      for (int g = 0; g < 16; ++g) {
        int lr = rb + wm + mi * 32 + cd_row(g, l);
        int bt = bn * 256 + wn + ni * 32 + (l & 31);
        Cb[(size_t)lr * 8192 + bt] = f2bf(acc[mi][ni][g]);
      }
}

// ---- generic batched A@B^T (both K-contig), scaled bf16 store ----------------
__global__ __launch_bounds__(512, 2) void k_gemm_bt(
    const uint16_t* __restrict__ A, int lda, long sA,
    const uint16_t* __restrict__ B, int ldb, long sB,
    uint16_t* __restrict__ C, int ldc, long sC,
    int K, float scale)
{
  const int z = blockIdx.z;
  A += (size_t)z * sA; B += (size_t)z * sB; C += (size_t)z * sC;
  const int tid = threadIdx.x;
  const int bm = blockIdx.y, bn = blockIdx.x;
  const int r0 = tid >> 2, co = stage_co();
  const uint16_t* aR0 = A + (size_t)(bm * 256 + r0) * lda + co;
  const uint16_t* aR1 = A + (size_t)(bm * 256 + 128 + r0) * lda + co;
  const uint16_t* bR0 = B + (size_t)(bn * 256 + r0) * ldb + co;
  const uint16_t* bR1 = B + (size_t)(bn * 256 + 128 + r0) * ldb + co;
  f32x16 acc[4][2];
#pragma unroll
  for (int i = 0; i < 4; ++i)
#pragma unroll
    for (int j = 0; j < 2; ++j)
#pragma unroll
      for (int g = 0; g < 16; ++g) acc[i][j][g] = 0.f;
  gemm256_core(aR0, aR1, bR0, bR1, K, acc);
  const int w = tid >> 6, l = tid & 63;
  const int wm = (w >> 2) * 128, wn = (w & 3) * 64;
#pragma unroll
  for (int mi = 0; mi < 4; ++mi)
#pragma unroll
    for (int ni = 0; ni < 2; ++ni)
#pragma unroll
      for (int g = 0; g < 16; ++g) {
        int grow = bm * 256 + wm + mi * 32 + cd_row(g, l);
        int gcol = bn * 256 + wn + ni * 32 + (l & 31);
        C[(size_t)grow * ldc + gcol] = f2bf(acc[mi][ni][g] * scale);
      }
}

// ---- stage D: permuted-A GEMM + fp32 bias/store into d_out -------------------
__device__ __forceinline__ size_t qrow_off(int rr) {
  // rr = b'*2048 + t' ; q row = (b_i, i), b_i=(t'>>4)&3, i=(t'&15)*128+b'*32+(t'>>6)
  int bp = rr >> 11, tp = rr & 2047;
  int bi = (tp >> 4) & 3;
  int i  = (tp & 15) * 128 + bp * 32 + (tp >> 6);
  return ((size_t)bi * 2048 + (size_t)i) * 2048;
}

__global__ __launch_bounds__(512, 2) void k_gemm_out(
    const uint16_t* __restrict__ Q,     // qb (4,2048,2048) bf16
    const uint16_t* __restrict__ W,     // wdb 2048x2048 bf16
    const float*    __restrict__ bias,  // b_dense fp32 (2048)
    float*          __restrict__ Out)   // d_out 8192x2048 fp32
{
  const int tid = threadIdx.x;
  const int bm = blockIdx.y, bn = blockIdx.x;
  const int r0 = tid >> 2, co = stage_co();
  const uint16_t* aR0 = Q + qrow_off(bm * 256 + r0) + co;
  const uint16_t* aR1 = Q + qrow_off(bm * 256 + 128 + r0) + co;
  const uint16_t* bR0 = W + (size_t)(bn * 256 + r0) * 2048 + co;
  const uint16_t* bR1 = W + (size_t)(bn * 256 + 128 + r0) * 2048 + co;
  f32x16 acc[4][2];
#pragma unroll
  for (int i = 0; i < 4; ++i)
#pragma unroll
    for (int j = 0; j < 2; ++j)
#pragma unroll
      for (int g = 0; g < 16; ++g) acc[i][j][g] = 0.f;
  gemm256_core(aR0, aR1, bR0, bR1, 2048, acc);
  const int w = tid >> 6, l = tid & 63;
  const int wm = (w >> 2) * 128, wn = (w & 3) * 64;
#pragma unroll
  for (int mi = 0; mi < 4; ++mi)
#pragma unroll
    for (int ni = 0; ni < 2; ++ni)
#pragma unroll
      for (int g = 0; g < 16; ++g) {
        int grow = bm * 256 + wm + mi * 32 + cd_row(g, l);
        int gcol = bn * 256 + wn + ni * 32 + (l & 31);
        Out[(size_t)grow * 2048 + gcol] = acc[mi][ni][g] + bias[gcol];
      }
}

// ---- transpose vT (2048x8192) -> Vn (8192x2048) ------------------------------
__global__ __launch_bounds__(256) void k_transpose(
    const uint16_t* __restrict__ src, uint16_t* __restrict__ dst)
{
  __shared__ uint16_t tile[64][65];
  const int tid = threadIdx.x;
  const int bx = blockIdx.x;
  const int by = blockIdx.y;
  const int cu = tid & 31, r0 = tid >> 5;
#pragma unroll
  for (int p = 0; p < 8; ++p) {
    int r = p * 8 + r0;
    uint32_t v = *reinterpret_cast<const uint32_t*>(
        &src[(size_t)(by * 64 + r) * 8192 + bx * 64 + cu * 2]);
    tile[r][cu * 2]     = (uint16_t)(v & 0xffffu);
    tile[r][cu * 2 + 1] = (uint16_t)(v >> 16);
  }
  __syncthreads();
#pragma unroll
  for (int p = 0; p < 8; ++p) {
    int r = p * 8 + r0;
    uint32_t lo = tile[cu * 2][r], hi = tile[cu * 2 + 1][r];
    *reinterpret_cast<uint32_t*>(
        &dst[(size_t)(bx * 64 + r) * 2048 + by * 64 + cu * 2]) = lo | (hi << 16);
  }
}

// ---- row softmax (bf16 in place), 1 block per row of 2048 --------------------
__global__ __launch_bounds__(256) void k_softmax(uint16_t* __restrict__ s)
{
  uint16_t* p = s + (size_t)blockIdx.x * 2048;
  const int tid = threadIdx.x;
  uint4 raw = reinterpret_cast<const uint4*>(p)[tid];
  uint32_t u[4] = {raw.x, raw.y, raw.z, raw.w};
  float x[8];
#pragma unroll
  for (int i = 0; i < 4; ++i) {
    x[2 * i]     = bf2f((uint16_t)(u[i] & 0xffffu));
    x[2 * i + 1] = bf2f((uint16_t)(u[i] >> 16));
  }
  float m = x[0];
#pragma unroll
  for (int i = 1; i < 8; ++i) m = fmaxf(m, x[i]);
#pragma unroll
  for (int o = 32; o; o >>= 1) m = fmaxf(m, __shfl_xor(m, o, 64));
  __shared__ float redm[4], reds[4];
  if ((tid & 63) == 0) redm[tid >> 6] = m;
  __syncthreads();
  m = fmaxf(fmaxf(redm[0], redm[1]), fmaxf(redm[2], redm[3]));
  float sum = 0.f;
#pragma unroll
  for (int i = 0; i < 8; ++i) { x[i] = __expf(x[i] - m); sum += x[i]; }
#pragma unroll
  for (int o = 32; o; o >>= 1) sum += __shfl_xor(sum, o, 64);
  if ((tid & 63) == 0) reds[tid >> 6] = sum;
  __syncthreads();
  sum = reds[0] + reds[1] + reds[2] + reds[3];
  float inv = 1.0f / sum;
  uint32_t ou[4];
#pragma unroll
  for (int i = 0; i < 4; ++i) {
    uint32_t lo = f2bf(x[2 * i] * inv);
    uint32_t hi = f2bf(x[2 * i + 1] * inv);
    ou[i] = lo | (hi << 16);
  }
  reinterpret_cast<uint4*>(p)[tid] = make_uint4(ou[0], ou[1], ou[2], ou[3]);
}

// ------------------------------------------------------------------------------
extern "C" void kernel_launch(void* const* d_in, const int* in_sizes, int n_in,
                              void* d_out, int out_size, void* d_ws, size_t ws_size,
                              hipStream_t stream) {
  const float* x       = (const float*)d_in[0];
  const float* w_qk    = (const float*)d_in[1];
  const float* w_dense = (const float*)d_in[2];
  const float* b_dense = (const float*)d_in[3];
  float* out = (float*)d_out;

  static int attr_done = 0;
  if (!attr_done) {
    (void)hipFuncSetAttribute(reinterpret_cast<const void*>(k_gemm_kv),
                              hipFuncAttributeMaxDynamicSharedMemorySize, 131072);
    (void)hipFuncSetAttribute(reinterpret_cast<const void*>(k_gemm_bt),
                              hipFuncAttributeMaxDynamicSharedMemorySize, 131072);
    (void)hipFuncSetAttribute(reinterpret_cast<const void*>(k_gemm_out),
                              hipFuncAttributeMaxDynamicSharedMemorySize, 131072);
    attr_done = 1;
  }

  const size_t NX = 4ull * 2048 * 2048;
  const size_t NW = 4096ull * 2048;
  const size_t ND = 2048ull * 2048;

  // d_ws layout (bf16): xb | wqkb | wdb | k0T | vT   (126 MB peak)
  uint16_t* xb   = (uint16_t*)d_ws;
  uint16_t* wqkb = xb + NX;
  uint16_t* wdb  = wqkb + NW;
  uint16_t* k0T  = wdb + ND;
  uint16_t* vT   = k0T + NX;
  uint16_t* qb   = xb;                    // alias: xb dead after stage A
  uint16_t* Vn   = (uint16_t*)d_out;      // d_out as scratch (dead before D)
  uint16_t* sb   = Vn + NX;

  const float scale = (float)(1.0 / sqrt(0.5 * 2048.0 * 2047.0));

  k_cast_all<<<dim3((NX4 + NW4 + ND4) / 256), 256, 0, stream>>>(x, w_qk, w_dense, xb);

  // A: kv^T  (M=4096 e, N=8192 bt, K=2048)
  k_gemm_kv<<<dim3(32, 16), 512, 131072, stream>>>(wqkb, xb, k0T, vT);
  // T: vT -> Vn
  k_transpose<<<dim3(128, 32), 256, 0, stream>>>(vT, Vn);
  // B: s = scale * k0T @ Vn^T
  k_gemm_bt<<<dim3(8, 8, 4), 512, 131072, stream>>>(
      k0T, 8192, 2048L, Vn, 2048, 2048L * 2048L, sb, 2048, 2048L * 2048L, 2048, scale);
  // S: softmax rows
  k_softmax<<<dim3(8192), 256, 0, stream>>>(sb);
  // C: q = a @ vT^T
  k_gemm_bt<<<dim3(8, 8, 4), 512, 131072, stream>>>(
      sb, 2048, 2048L * 2048L, vT, 8192, 2048L, qb, 2048, 2048L * 2048L, 2048, 1.0f);
  // D: out = perm(q) @ w_dense^T + bias -> fp32
  k_gemm_out<<<dim3(8, 32), 512, 131072, stream>>>(qb, wdb, b_dense, out);
}